// Round 8
// baseline (9289.323 us; speedup 1.0000x reference)
//
#include <hip/hip_runtime.h>
#include <cstdint>
#include <cstddef>

// Problem constants (B=8, N=2048, M=256)
#define NB 8
#define NN 2048
#define MM 256

typedef unsigned long long u64;

// monotone float->uint map; canonicalize -0 to +0 so float ties == key ties
__device__ __forceinline__ unsigned mapf(float f) {
  unsigned u = __float_as_uint(f + 0.f);
  return ((int)u >= 0) ? (u ^ 0x80000000u) : ~u;
}
__device__ __forceinline__ u64 shflx_u64(u64 v, int m) {
  unsigned lo = (unsigned)__shfl_xor((int)(unsigned)v, m);
  unsigned hi = (unsigned)__shfl_xor((int)(v >> 32), m);
  return ((u64)hi << 32) | lo;
}
__device__ __forceinline__ u64 agent_load(const u64* p) {
  return __hip_atomic_load(p, __ATOMIC_RELAXED, __HIP_MEMORY_SCOPE_AGENT);
}

// ---------------------------------------------------------------------------
// Phase A: LSTM trajectory — gate-aligned waves + pipelined poll.
//
// grid(NB,8) x 1024 thr (16 waves). Block (b,q) owns m-slice [32q,32q+32).
// ROW REMAP vs round 5 (2899us verified): wave w owns m-local {2w, 2w+1}
// with ALL FOUR GATES in-wave. lane = 8*r8 + c8, r8 = 2g+p, p = m-parity:
// one row per lane (32-fma chain, same as round 5; round 7's two-rows-per-
// lane at 512thr halved occupancy and doubled the chain -> regressed).
// After the c8-butterfly each lane holds its row's full gate preact; 4 shfls
// gather (i,f,g,o) for m=2w+p; cell update runs in-wave; lanes (r8<2,c8==0)
// publish. This deletes round 5's BAR B + act-LDS round-trip + wave-0
// funnel: ONE barrier per step, publish ~400cy after BAR A (tight burst).
//
// POLL: 3-deep pipelined sampler. Three relaxed agent loads to the same
// address stay in flight; check the oldest, reissue on miss. Sampling
// period ~RT/3 instead of ~RT -> discovery overshoot and (critically) the
// jitter that the 64-block convoy maxes over both shrink. If the compiler
// serializes the atomics this degenerates to round 5's poll (neutral).
//
// Exchange medium unchanged (the only survivor of rounds 0-6): LLC relaxed
// agent-scope atomics, PACKED words (round 6: padding = 13x fetch
// amplification, regressed), tagged u64, parity double-buffer, Pbuf zeroed
// at launch (tag 0 never awaited).
// Progress/overwrite safety (same induction as rounds 5/7): publishing tag
// tt+1 requires passing poll(tt) [all blocks published tt], which requires
// every block's waves past BAR(tt-1), hence all consumption of tag tt-1
// (the slot being overwritten) complete. hbuf parity double-buffer makes
// the single barrier sound: step tt polls write hbuf[tt&1]; the slowest
// wave can only be in step tt-1 reading hbuf[(tt-1)&1].
// Matvec LDS reads: c8-rotated slot order with pre-rotated weight registers
// (8 distinct float4 spans x 8-lane broadcast = conflict-free; verified 0
// SQ_LDS_BANK_CONFLICT since round 2).
// ---------------------------------------------------------------------------
__global__ __launch_bounds__(1024) void lstm_kernel(
    const float* __restrict__ z_g, const float* __restrict__ dec,
    const float* __restrict__ h0, const float* __restrict__ w_ih,
    const float* __restrict__ w_hh, const float* __restrict__ b_ih,
    const float* __restrict__ b_hh, float* __restrict__ Hall,
    u64* __restrict__ Pbuf)
{
  const int b = blockIdx.x;
  const int q = blockIdx.y;
  const int tid = threadIdx.x;
  const int w = tid >> 6;          // wave 0..15 -> m-local {2w, 2w+1}
  const int lane = tid & 63;
  const int r8 = lane >> 3;        // 0..7 = 2g+p
  const int c8 = lane & 7;         // col segment 0..7
  const int g = r8 >> 1;           // gate 0..3 (i,f,g,o)
  const int p = r8 & 1;            // m parity
  const int ml = 2 * w + p;        // m-local 0..31
  const int grow = g * 256 + 32 * q + ml;

  __shared__ __align__(16) float hbuf[2][256];

  // recurrent weights, pre-rotated by c8 (conflict-free matvec reads):
  // slot jj holds cols 32*c8 + 4*((jj+c8)&7) .. +3
  float wreg[32];
  {
    const float* wr = w_hh + (size_t)grow * MM + 32 * c8;
    #pragma unroll
    for (int jj = 0; jj < 8; ++jj) {
      float4 v = *(const float4*)(wr + 4 * ((jj + c8) & 7));
      wreg[4 * jj + 0] = v.x; wreg[4 * jj + 1] = v.y;
      wreg[4 * jj + 2] = v.z; wreg[4 * jj + 3] = v.w;
    }
  }

  // xb = (dec @ w_ih.T)[grow] + b_ih[grow] + b_hh[grow] (c8-butterfly)
  float xb;
  {
    const float* wr = w_ih + (size_t)grow * MM + 32 * c8;
    float pcc = 0.f;
    #pragma unroll
    for (int i = 0; i < 8; ++i) {
      float4 wv = *(const float4*)(wr + 4 * i);
      float4 dv = *(const float4*)(dec + 32 * c8 + 4 * i);
      pcc += wv.x * dv.x + wv.y * dv.y + wv.z * dv.z + wv.w * dv.w;
    }
    pcc += __shfl_xor(pcc, 1); pcc += __shfl_xor(pcc, 2); pcc += __shfl_xor(pcc, 4);
    xb = pcc + b_ih[grow] + b_hh[grow];
  }

  float c_my = z_g[b * MM + 32 * q + ml];
  if (tid < 256) hbuf[0][tid] = h0[tid];

  u64* Pb = Pbuf + (size_t)b * 512;
  float* Hb = Hall + (size_t)b * NN * MM;

  const bool istanh = (g == 2);
  const float kmul = istanh ? -2.f : -1.f;

  for (int tt = 0; tt < NN; ++tt) {
    // ---- poll h^(tt) into hbuf[tt&1] (waves 0-3; 3-deep pipelined) ----
    if (tt > 0 && w < 4) {
      const int widx = (w << 6) + lane;
      const u64* pa = Pb + ((tt & 1) << 8) + widx;
      const unsigned tg = (unsigned)tt;
      u64 v0 = agent_load(pa);
      u64 v1 = agent_load(pa);
      u64 v2 = agent_load(pa);
      u64 v;
      for (;;) {
        if (__all((int)((unsigned)(v0 >> 32) == tg))) { v = v0; break; }
        v0 = agent_load(pa);
        if (__all((int)((unsigned)(v1 >> 32) == tg))) { v = v1; break; }
        v1 = agent_load(pa);
        if (__all((int)((unsigned)(v2 >> 32) == tg))) { v = v2; break; }
        v2 = agent_load(pa);
      }
      hbuf[tt & 1][widx] = __uint_as_float((unsigned)v);
    }
    __syncthreads();                       // the ONE barrier per step

    // ---- matvec over this lane's 32-col segment (rotated reads) ----
    const float4* h4 = (const float4*)hbuf[tt & 1];
    float a0 = 0.f, a1 = 0.f, a2 = 0.f, a3 = 0.f;
    #pragma unroll
    for (int jj = 0; jj < 8; ++jj) {
      float4 hv = h4[8 * c8 + ((jj + c8) & 7)];
      a0 = fmaf(hv.x, wreg[4 * jj + 0], a0);
      a1 = fmaf(hv.y, wreg[4 * jj + 1], a1);
      a2 = fmaf(hv.z, wreg[4 * jj + 2], a2);
      a3 = fmaf(hv.w, wreg[4 * jj + 3], a3);
    }
    float s = (a0 + a1) + (a2 + a3);
    s += __shfl_xor(s, 1); s += __shfl_xor(s, 2); s += __shfl_xor(s, 4);
    const float gsum = s + xb;

    // activation (branchless: lanes differ in g within the wave)
    const float e = __expf(kmul * gsum);
    const float sg = 1.f / (1.f + e);
    const float a = istanh ? 2.f * sg - 1.f : sg;

    // ---- in-wave gate gather for m = 2w+p ----
    const int bl = 8 * p + c8;
    const float gi  = __shfl(a, bl);           // gate i: r8 = p
    const float gf  = __shfl(a, 16 + bl);      // gate f: r8 = 2+p
    const float gg_ = __shfl(a, 32 + bl);      // gate g: r8 = 4+p
    const float go  = __shfl(a, 48 + bl);      // gate o: r8 = 6+p

    // ---- cell update (redundant x32 lanes per m; identical FP ops) ----
    c_my = gf * c_my + gi * gg_;
    const float e2 = __expf(-2.f * c_my);
    const float hn = go * (2.f / (1.f + e2) - 1.f);

    // ---- publish: lanes (r8<2, c8==0) own m = 2w+r8 ----
    if (r8 < 2 && c8 == 0) {
      const int mi = 32 * q + ml;              // ml = 2w+p, p = r8 here
      const u64 pk = ((u64)(unsigned)(tt + 1) << 32) | (u64)__float_as_uint(hn);
      __hip_atomic_store(Pb + (((tt + 1) & 1) << 8) + mi, pk,
                         __ATOMIC_RELAXED, __HIP_MEMORY_SCOPE_AGENT);
      Hb[(size_t)tt * MM + mi] = hn;           // trajectory for the Q gemm
    }
  }
}

// ---------------------------------------------------------------------------
// C = A @ B^T (+ col bias). 128x128 tile, 256 threads, 8x8 micro-tile.
// ---------------------------------------------------------------------------
__global__ __launch_bounds__(256) void gemm128(
    const float* __restrict__ A, const float* __restrict__ B,
    float* __restrict__ C, const float* __restrict__ bias,
    int K, int Ncol, long sA, long sB, long sC)
{
  __shared__ __align__(16) float As[32][132];
  __shared__ __align__(16) float Bs[32][132];
  const int tid = threadIdx.x;
  const int tx = tid & 15;
  const int ty = tid >> 4;
  const int row0 = blockIdx.y * 128;
  const int col0 = blockIdx.x * 128;
  const float* Ab = A + (size_t)blockIdx.z * (size_t)sA;
  const float* Bb = B + (size_t)blockIdx.z * (size_t)sB;
  float* Cb = C + (size_t)blockIdx.z * (size_t)sC;

  float acc[8][8];
  #pragma unroll
  for (int i = 0; i < 8; ++i)
    #pragma unroll
    for (int jj = 0; jj < 8; ++jj) acc[i][jj] = 0.f;

  for (int k0 = 0; k0 < K; k0 += 32) {
    #pragma unroll
    for (int it = 0; it < 4; ++it) {
      const int idx = tid + it * 256;
      const int r = idx >> 3;
      const int c4 = (idx & 7) << 2;
      float4 va = *(const float4*)(Ab + (size_t)(row0 + r) * K + k0 + c4);
      float4 vb = *(const float4*)(Bb + (size_t)(col0 + r) * K + k0 + c4);
      As[c4 + 0][r] = va.x; As[c4 + 1][r] = va.y;
      As[c4 + 2][r] = va.z; As[c4 + 3][r] = va.w;
      Bs[c4 + 0][r] = vb.x; Bs[c4 + 1][r] = vb.y;
      Bs[c4 + 2][r] = vb.z; Bs[c4 + 3][r] = vb.w;
    }
    __syncthreads();
    #pragma unroll
    for (int kk = 0; kk < 32; ++kk) {
      float4 a0 = *(const float4*)&As[kk][ty * 4];
      float4 a1 = *(const float4*)&As[kk][64 + ty * 4];
      float4 b0 = *(const float4*)&Bs[kk][tx * 4];
      float4 b1 = *(const float4*)&Bs[kk][64 + tx * 4];
      const float av[8] = {a0.x, a0.y, a0.z, a0.w, a1.x, a1.y, a1.z, a1.w};
      const float bv[8] = {b0.x, b0.y, b0.z, b0.w, b1.x, b1.y, b1.z, b1.w};
      #pragma unroll
      for (int i = 0; i < 8; ++i)
        #pragma unroll
        for (int jj = 0; jj < 8; ++jj)
          acc[i][jj] = fmaf(av[i], bv[jj], acc[i][jj]);
    }
    __syncthreads();
  }

  #pragma unroll
  for (int i = 0; i < 8; ++i) {
    const int r = row0 + ((i < 4) ? (ty * 4 + i) : (64 + ty * 4 + i - 4));
    float* cp = Cb + (size_t)r * Ncol + col0;
    float4 o0, o1;
    float* o0p = &o0.x; float* o1p = &o1.x;
    #pragma unroll
    for (int jj = 0; jj < 4; ++jj) {
      float v0 = acc[i][jj], v1 = acc[i][jj + 4];
      if (bias) {
        v0 += bias[col0 + tx * 4 + jj];
        v1 += bias[col0 + 64 + tx * 4 + jj];
      }
      o0p[jj] = v0; o1p[jj] = v1;
    }
    *(float4*)(cp + tx * 4) = o0;
    *(float4*)(cp + 64 + tx * 4) = o1;
  }
}

// ---------------------------------------------------------------------------
// Phase D: exact greedy masked argmax chain, one block (512 thr) per batch.
// ---------------------------------------------------------------------------
__global__ __launch_bounds__(512) void select_block(
    const float* __restrict__ S, int* __restrict__ sel)
{
  const int b = blockIdx.x;
  const int tid = threadIdx.x;
  const int w = tid >> 6;          // 0..7
  const int lane = tid & 63;
  const float* Sb = S + (size_t)b * NN * NN + 4 * tid;
  int* selb = sel + b * NN;

  __shared__ u64 partial[2][8];

  for (int i = tid; i < NN; i += 512) selb[i] = 0x7fffffff;
  __syncthreads();

  unsigned mybits = 0;                 // used flags for my 4 columns
  const unsigned base = 2047u - 4u * (unsigned)tid;

  auto stepf = [&](float4 v, int t) {
    u64 k0 = (mybits & 1u) ? 0 : (((u64)mapf(v.x) << 32) | (base - 0u));
    u64 k1 = (mybits & 2u) ? 0 : (((u64)mapf(v.y) << 32) | (base - 1u));
    u64 k2 = (mybits & 4u) ? 0 : (((u64)mapf(v.z) << 32) | (base - 2u));
    u64 k3 = (mybits & 8u) ? 0 : (((u64)mapf(v.w) << 32) | (base - 3u));
    u64 k = k0 > k1 ? k0 : k1;
    if (k2 > k) k = k2;
    if (k3 > k) k = k3;
    #pragma unroll
    for (int off = 1; off < 64; off <<= 1) {
      u64 o = shflx_u64(k, off);
      if (o > k) k = o;
    }
    if (lane == 0) partial[t & 1][w] = k;
    __syncthreads();
    u64 pk = partial[t & 1][lane & 7];
    #pragma unroll
    for (int off = 1; off < 8; off <<= 1) {
      u64 o = shflx_u64(pk, off);
      if (o > pk) pk = o;
    }
    const int idx = 2047 - (int)(pk & 0x7ff);
    if ((idx >> 2) == tid) mybits |= 1u << (idx & 3);
    if (tid == 0) selb[idx] = t;
  };

  float4 r0 = *(const float4*)(Sb + (size_t)0 * NN);
  float4 r1 = *(const float4*)(Sb + (size_t)1 * NN);
  float4 r2 = *(const float4*)(Sb + (size_t)2 * NN);
  float4 r3 = *(const float4*)(Sb + (size_t)3 * NN);
  for (int t = 0; t < NN; t += 4) {
    const size_t p4 = (size_t)((t + 4 < NN) ? t + 4 : NN - 1) * NN;
    const size_t p5 = (size_t)((t + 5 < NN) ? t + 5 : NN - 1) * NN;
    const size_t p6 = (size_t)((t + 6 < NN) ? t + 6 : NN - 1) * NN;
    const size_t p7 = (size_t)((t + 7 < NN) ? t + 7 : NN - 1) * NN;
    stepf(r0, t);     r0 = *(const float4*)(Sb + p4);
    stepf(r1, t + 1); r1 = *(const float4*)(Sb + p5);
    stepf(r2, t + 2); r2 = *(const float4*)(Sb + p6);
    stepf(r3, t + 3); r3 = *(const float4*)(Sb + p7);
  }
}

// ---------------------------------------------------------------------------
// Phase E: in-place masked softmax per row. Row t masks n iff sel[n] < t.
// ---------------------------------------------------------------------------
__global__ __launch_bounds__(256) void softmax_kernel(
    float* __restrict__ out, const int* __restrict__ sel)
{
  const int t = blockIdx.x;
  const int b = blockIdx.y;
  const int tid = threadIdx.x;
  float* row = out + ((size_t)b * NN + t) * NN;
  const int* selb = sel + b * NN;
  __shared__ float red[8];

  float v[8];
  int sl[8];
  #pragma unroll
  for (int u = 0; u < 2; ++u) {
    float4 f = *(const float4*)(row + u * 1024 + tid * 4);
    int4 s4 = *(const int4*)(selb + u * 1024 + tid * 4);
    v[u * 4 + 0] = f.x; v[u * 4 + 1] = f.y; v[u * 4 + 2] = f.z; v[u * 4 + 3] = f.w;
    sl[u * 4 + 0] = s4.x; sl[u * 4 + 1] = s4.y; sl[u * 4 + 2] = s4.z; sl[u * 4 + 3] = s4.w;
  }

  float mx = -3.0e38f;
  #pragma unroll
  for (int e = 0; e < 8; ++e)
    if (sl[e] >= t) mx = fmaxf(mx, v[e]);
  #pragma unroll
  for (int off = 1; off < 64; off <<= 1) mx = fmaxf(mx, __shfl_xor(mx, off));
  if ((tid & 63) == 0) red[tid >> 6] = mx;
  __syncthreads();
  mx = fmaxf(fmaxf(red[0], red[1]), fmaxf(red[2], red[3]));

  float e8[8];
  float sum = 0.f;
  #pragma unroll
  for (int e = 0; e < 8; ++e) {
    float ex = (sl[e] >= t) ? __expf(v[e] - mx) : 0.f;
    e8[e] = ex;
    sum += ex;
  }
  #pragma unroll
  for (int off = 1; off < 64; off <<= 1) sum += __shfl_xor(sum, off);
  if ((tid & 63) == 0) red[4 + (tid >> 6)] = sum;
  __syncthreads();
  sum = red[4] + red[5] + red[6] + red[7];
  const float inv = 1.f / sum;

  #pragma unroll
  for (int u = 0; u < 2; ++u) {
    float4 o;
    o.x = e8[u * 4 + 0] * inv; o.y = e8[u * 4 + 1] * inv;
    o.z = e8[u * 4 + 2] * inv; o.w = e8[u * 4 + 3] * inv;
    *(float4*)(row + u * 1024 + tid * 4) = o;
  }
}

// ---------------------------------------------------------------------------
// ws layout (floats): keys[4194304] | Q[4194304] | Pbuf(u64 4096 = 32KB,
//                     PACKED) | sel[16384]   ~ 33.7 MB
// Hall (h trajectory, [B][NN][256] f32 = 16.8MB) borrows d_out (134MB),
// consumed by the Q gemm before gemm2 overwrites it.
// ---------------------------------------------------------------------------
extern "C" void kernel_launch(void* const* d_in, const int* in_sizes, int n_in,
                              void* d_out, int out_size, void* d_ws, size_t ws_size,
                              hipStream_t stream)
{
  (void)in_sizes; (void)n_in; (void)out_size; (void)ws_size;
  const float* emb  = (const float*)d_in[0];
  const float* z_g  = (const float*)d_in[1];
  const float* dec  = (const float*)d_in[2];
  const float* h0   = (const float*)d_in[3];
  const float* w_ih = (const float*)d_in[4];
  const float* w_hh = (const float*)d_in[5];
  const float* b_ih = (const float*)d_in[6];
  const float* b_hh = (const float*)d_in[7];
  const float* Wq   = (const float*)d_in[8];
  const float* bq   = (const float*)d_in[9];
  const float* Wk   = (const float*)d_in[10];
  const float* bk   = (const float*)d_in[11];
  float* out = (float*)d_out;
  float* ws  = (float*)d_ws;

  float* keys  = ws;
  float* Q     = ws + 4194304;
  u64*   Pbuf  = (u64*)(ws + 8388608);    // 4096 u64 = 32 KB (packed)
  int*   sel   = (int*)(ws + 8396800);
  float* Hall  = out;                     // borrowed until the Q gemm

  // zero exchange tags (tag 0 never awaited; awaited tags >= 1)
  hipMemsetAsync(Pbuf, 0, 4096 * sizeof(u64), stream);

  lstm_kernel<<<dim3(NB, 8), 1024, 0, stream>>>(
      z_g, dec, h0, w_ih, w_hh, b_ih, b_hh, Hall, Pbuf);

  // Q = Hall @ Wq.T + bq  ([16384,256] x [256,256]^T)
  gemm128<<<dim3(MM / 128, (NB * NN) / 128, 1), 256, 0, stream>>>(
      Hall, Wq, Q, bq, MM, MM, 0, 0, 0);

  // keys = emb @ Wk.T + bk
  gemm128<<<dim3(MM / 128, (NB * NN) / 128, 1), 256, 0, stream>>>(
      emb, Wk, keys, bk, MM, MM, 0, 0, 0);

  // S[b] = Q[b] @ keys[b].T -> d_out (overwrites Hall, already consumed)
  gemm128<<<dim3(NN / 128, NN / 128, NB), 256, 0, stream>>>(
      Q, keys, out, nullptr, MM, NN,
      (long)NN * MM, (long)NN * MM, (long)NN * NN);

  select_block<<<NB, 512, 0, stream>>>(out, sel);

  softmax_kernel<<<dim3(NN, NB), 256, 0, stream>>>(out, sel);
}

// Round 9
// 4706.664 us; speedup vs baseline: 1.9737x; 1.9737x over previous
//
#include <hip/hip_runtime.h>
#include <cstdint>
#include <cstddef>

// Problem constants (B=8, N=2048, M=256)
#define NB 8
#define NN 2048
#define MM 256

typedef unsigned long long u64;

// monotone float->uint map; canonicalize -0 to +0 so float ties == key ties
__device__ __forceinline__ unsigned mapf(float f) {
  unsigned u = __float_as_uint(f + 0.f);
  return ((int)u >= 0) ? (u ^ 0x80000000u) : ~u;
}
__device__ __forceinline__ u64 shflx_u64(u64 v, int m) {
  unsigned lo = (unsigned)__shfl_xor((int)(unsigned)v, m);
  unsigned hi = (unsigned)__shfl_xor((int)(v >> 32), m);
  return ((u64)hi << 32) | lo;
}
__device__ __forceinline__ u64 agent_load(const u64* p) {
  return __hip_atomic_load(p, __ATOMIC_RELAXED, __HIP_MEMORY_SCOPE_AGENT);
}

// ---------------------------------------------------------------------------
// Phase A: LSTM trajectory — round-5 structure (2899us verified) with the
// poll consolidated into ONE wave.
//
// Why (round-8 post-mortem laws):
//  * publish = ONE dense 32-lane store (scattered 8B stores each dirty a
//    64B HBM sector: round 8 WRITE_SIZE +33MB, regressed).
//  * poll rate ~1 probe/RT, wave-coalesced (round 8's 3-deep poll tripled
//    FETCH, regressed; round 6 padding = 13x fetch, regressed).
//  * NEW: all 256 words sampled at a SINGLE phase (wave 0 polls everything:
//    lane l -> words l, 64+l, 128+l, 192+l; each load inst is 64 consecutive
//    words = 4 cachelines). With one sampling phase, discovery = first sample
//    after last arrival (~+RT/2) instead of max over ~32 independent wave
//    phases (~+RT). Fewer pollers, same line-request count as round 5.
//  * own-slice shortcut: the tail writes its own 32 hn into hbuf directly;
//    the poller treats own-slice words as satisfied -> our own store's LLC
//    visibility drops out of the critical max.
//
// Everything else identical to round 5: block (b,q) owns m-slice
// [32q,32q+32) -> 128 gate rows; wave w rows lr=8w..8w+7; lane=8*(lr&7)+c8;
// c8-butterfly reduce; act LDS hop; wave-0 tail (2 rows/lane, shfl_xor 32
// pairing, lanes<32 cell update + dense publish). Exchange: LLC relaxed
// agent atomics, PACKED tagged u64, parity double-buffered Pbuf slots,
// zeroed at launch (tag 0 never awaited). Progress: publishing tag tt+1
// requires passing poll(tt); polled slot's tags can only be <tt or ==tt
// (a remote can be at most one step ahead, writing the OTHER parity slot).
// ---------------------------------------------------------------------------
__global__ __launch_bounds__(1024) void lstm_kernel(
    const float* __restrict__ z_g, const float* __restrict__ dec,
    const float* __restrict__ h0, const float* __restrict__ w_ih,
    const float* __restrict__ w_hh, const float* __restrict__ b_ih,
    const float* __restrict__ b_hh, float* __restrict__ Hall,
    u64* __restrict__ Pbuf)
{
  const int b = blockIdx.x;
  const int q = blockIdx.y;
  const int tid = threadIdx.x;
  const int w = tid >> 6;
  const int lane = tid & 63;
  const int rr = lane >> 3;        // row within wave 0..7
  const int c8 = lane & 7;         // col segment 0..7
  const int lr = 8 * w + rr;       // local gate row 0..127
  const int g = lr >> 5;           // gate 0..3 (i,f,g,o) — wave-uniform
  const int m = lr & 31;
  const int grow = g * 256 + 32 * q + m;

  __shared__ __align__(16) float hbuf[256];
  __shared__ __align__(16) float act[128];

  // recurrent weights, pre-rotated by c8 so the matvec LDS reads are
  // conflict-free: wreg slot jj holds cols 32*c8 + 4*((jj+c8)&7) ..+3
  float wreg[32];
  {
    const float* wr = w_hh + (size_t)grow * MM + 32 * c8;
    #pragma unroll
    for (int jj = 0; jj < 8; ++jj) {
      float4 v = *(const float4*)(wr + 4 * ((jj + c8) & 7));
      wreg[4 * jj + 0] = v.x; wreg[4 * jj + 1] = v.y;
      wreg[4 * jj + 2] = v.z; wreg[4 * jj + 3] = v.w;
    }
  }

  // xb = (dec @ w_ih.T)[grow] + b_ih[grow] + b_hh[grow] (c8-butterfly)
  float xb;
  {
    const float* wr = w_ih + (size_t)grow * MM + 32 * c8;
    float p = 0.f;
    #pragma unroll
    for (int i = 0; i < 8; ++i) {
      float4 wv = *(const float4*)(wr + 4 * i);
      float4 dv = *(const float4*)(dec + 32 * c8 + 4 * i);
      p += wv.x * dv.x + wv.y * dv.y + wv.z * dv.z + wv.w * dv.w;
    }
    p += __shfl_xor(p, 1); p += __shfl_xor(p, 2); p += __shfl_xor(p, 4);
    xb = p + b_ih[grow] + b_hh[grow];
  }

  float c_my = 0.f;
  if (tid < 32) c_my = z_g[b * MM + 32 * q + tid];
  if (tid < 256) hbuf[tid] = h0[tid];

  u64* Pb = Pbuf + (size_t)b * 512;
  float* Hb = Hall + (size_t)b * NN * MM + 32 * q;

  // own-slice membership of the 4 polled strides (per-lane constants)
  const bool own0 = ((lane >> 5) + 0) == q;   // word lane
  const bool own1 = ((lane >> 5) + 2) == q;   // word 64+lane
  const bool own2 = ((lane >> 5) + 4) == q;   // word 128+lane
  const bool own3 = ((lane >> 5) + 6) == q;   // word 192+lane

  for (int tt = 0; tt < NN; ++tt) {
    // ---- poll h^(tt): ONE wave, single sampling phase ----
    if (tt > 0 && w == 0) {
      const u64* pa = Pb + ((tt & 1) << 8);
      const unsigned tg = (unsigned)tt;
      u64 a0, a1, a2, a3;
      for (;;) {
        a0 = agent_load(pa + lane);
        a1 = agent_load(pa + 64 + lane);
        a2 = agent_load(pa + 128 + lane);
        a3 = agent_load(pa + 192 + lane);
        const bool ok = (own0 | ((unsigned)(a0 >> 32) == tg))
                      & (own1 | ((unsigned)(a1 >> 32) == tg))
                      & (own2 | ((unsigned)(a2 >> 32) == tg))
                      & (own3 | ((unsigned)(a3 >> 32) == tg));
        if (__all((int)ok)) break;
      }
      // own-slice words were written to hbuf by the tail (same bits)
      if (!own0) hbuf[lane]       = __uint_as_float((unsigned)a0);
      if (!own1) hbuf[64 + lane]  = __uint_as_float((unsigned)a1);
      if (!own2) hbuf[128 + lane] = __uint_as_float((unsigned)a2);
      if (!own3) hbuf[192 + lane] = __uint_as_float((unsigned)a3);
    }
    __syncthreads();                                  // BAR A

    // ---- matvec over this lane's 32-col segment (rotated, no conflicts) --
    const float4* h4 = (const float4*)hbuf;
    float a0 = 0.f, a1 = 0.f, a2 = 0.f, a3 = 0.f;
    #pragma unroll
    for (int jj = 0; jj < 8; ++jj) {
      float4 hv = h4[8 * c8 + ((jj + c8) & 7)];
      a0 = fmaf(hv.x, wreg[4 * jj + 0], a0);
      a1 = fmaf(hv.y, wreg[4 * jj + 1], a1);
      a2 = fmaf(hv.z, wreg[4 * jj + 2], a2);
      a3 = fmaf(hv.w, wreg[4 * jj + 3], a3);
    }
    float s = (a0 + a1) + (a2 + a3);
    s += __shfl_xor(s, 1); s += __shfl_xor(s, 2); s += __shfl_xor(s, 4);
    const float gsum = s + xb;

    // activation (wave-uniform branch: g = w>>2)
    float a;
    if ((w >> 2) == 2) { const float e = __expf(-2.f * gsum); a = 2.f / (1.f + e) - 1.f; }
    else               { a = 1.f / (1.f + __expf(-gsum)); }
    if (c8 == 0) act[lr] = a;
    __syncthreads();                                  // BAR B

    // ---- wave-0 tail: cell update + dense publish (32 lanes, one store) --
    if (tid < 32) {
      const float i_g = act[tid], f_g = act[32 + tid];
      const float g_g = act[64 + tid], o_g = act[96 + tid];
      c_my = f_g * c_my + i_g * g_g;
      const float e2 = __expf(-2.f * c_my);
      const float hn = o_g * (2.f / (1.f + e2) - 1.f);
      const u64 pk = ((u64)(unsigned)(tt + 1) << 32) | (u64)__float_as_uint(hn);
      __hip_atomic_store(Pb + (((tt + 1) & 1) << 8) + 32 * q + tid, pk,
                         __ATOMIC_RELAXED, __HIP_MEMORY_SCOPE_AGENT);
      hbuf[32 * q + tid] = hn;           // own-slice shortcut for next poll
      Hb[(size_t)tt * MM + tid] = hn;    // trajectory for the Q gemm
    }
    // no barrier: hbuf writes (tail + next poll, both wave 0 post-BAR B /
    // pre-BAR A) are ordered against all matvec reads by BAR A/BAR B.
  }
}

// ---------------------------------------------------------------------------
// C = A @ B^T (+ col bias). 128x128 tile, 256 threads, 8x8 micro-tile.
// ---------------------------------------------------------------------------
__global__ __launch_bounds__(256) void gemm128(
    const float* __restrict__ A, const float* __restrict__ B,
    float* __restrict__ C, const float* __restrict__ bias,
    int K, int Ncol, long sA, long sB, long sC)
{
  __shared__ __align__(16) float As[32][132];
  __shared__ __align__(16) float Bs[32][132];
  const int tid = threadIdx.x;
  const int tx = tid & 15;
  const int ty = tid >> 4;
  const int row0 = blockIdx.y * 128;
  const int col0 = blockIdx.x * 128;
  const float* Ab = A + (size_t)blockIdx.z * (size_t)sA;
  const float* Bb = B + (size_t)blockIdx.z * (size_t)sB;
  float* Cb = C + (size_t)blockIdx.z * (size_t)sC;

  float acc[8][8];
  #pragma unroll
  for (int i = 0; i < 8; ++i)
    #pragma unroll
    for (int jj = 0; jj < 8; ++jj) acc[i][jj] = 0.f;

  for (int k0 = 0; k0 < K; k0 += 32) {
    #pragma unroll
    for (int it = 0; it < 4; ++it) {
      const int idx = tid + it * 256;
      const int r = idx >> 3;
      const int c4 = (idx & 7) << 2;
      float4 va = *(const float4*)(Ab + (size_t)(row0 + r) * K + k0 + c4);
      float4 vb = *(const float4*)(Bb + (size_t)(col0 + r) * K + k0 + c4);
      As[c4 + 0][r] = va.x; As[c4 + 1][r] = va.y;
      As[c4 + 2][r] = va.z; As[c4 + 3][r] = va.w;
      Bs[c4 + 0][r] = vb.x; Bs[c4 + 1][r] = vb.y;
      Bs[c4 + 2][r] = vb.z; Bs[c4 + 3][r] = vb.w;
    }
    __syncthreads();
    #pragma unroll
    for (int kk = 0; kk < 32; ++kk) {
      float4 a0 = *(const float4*)&As[kk][ty * 4];
      float4 a1 = *(const float4*)&As[kk][64 + ty * 4];
      float4 b0 = *(const float4*)&Bs[kk][tx * 4];
      float4 b1 = *(const float4*)&Bs[kk][64 + tx * 4];
      const float av[8] = {a0.x, a0.y, a0.z, a0.w, a1.x, a1.y, a1.z, a1.w};
      const float bv[8] = {b0.x, b0.y, b0.z, b0.w, b1.x, b1.y, b1.z, b1.w};
      #pragma unroll
      for (int i = 0; i < 8; ++i)
        #pragma unroll
        for (int jj = 0; jj < 8; ++jj)
          acc[i][jj] = fmaf(av[i], bv[jj], acc[i][jj]);
    }
    __syncthreads();
  }

  #pragma unroll
  for (int i = 0; i < 8; ++i) {
    const int r = row0 + ((i < 4) ? (ty * 4 + i) : (64 + ty * 4 + i - 4));
    float* cp = Cb + (size_t)r * Ncol + col0;
    float4 o0, o1;
    float* o0p = &o0.x; float* o1p = &o1.x;
    #pragma unroll
    for (int jj = 0; jj < 4; ++jj) {
      float v0 = acc[i][jj], v1 = acc[i][jj + 4];
      if (bias) {
        v0 += bias[col0 + tx * 4 + jj];
        v1 += bias[col0 + 64 + tx * 4 + jj];
      }
      o0p[jj] = v0; o1p[jj] = v1;
    }
    *(float4*)(cp + tx * 4) = o0;
    *(float4*)(cp + 64 + tx * 4) = o1;
  }
}

// ---------------------------------------------------------------------------
// Phase D: exact greedy masked argmax chain, one block (512 thr) per batch.
// ---------------------------------------------------------------------------
__global__ __launch_bounds__(512) void select_block(
    const float* __restrict__ S, int* __restrict__ sel)
{
  const int b = blockIdx.x;
  const int tid = threadIdx.x;
  const int w = tid >> 6;          // 0..7
  const int lane = tid & 63;
  const float* Sb = S + (size_t)b * NN * NN + 4 * tid;
  int* selb = sel + b * NN;

  __shared__ u64 partial[2][8];

  for (int i = tid; i < NN; i += 512) selb[i] = 0x7fffffff;
  __syncthreads();

  unsigned mybits = 0;                 // used flags for my 4 columns
  const unsigned base = 2047u - 4u * (unsigned)tid;

  auto stepf = [&](float4 v, int t) {
    u64 k0 = (mybits & 1u) ? 0 : (((u64)mapf(v.x) << 32) | (base - 0u));
    u64 k1 = (mybits & 2u) ? 0 : (((u64)mapf(v.y) << 32) | (base - 1u));
    u64 k2 = (mybits & 4u) ? 0 : (((u64)mapf(v.z) << 32) | (base - 2u));
    u64 k3 = (mybits & 8u) ? 0 : (((u64)mapf(v.w) << 32) | (base - 3u));
    u64 k = k0 > k1 ? k0 : k1;
    if (k2 > k) k = k2;
    if (k3 > k) k = k3;
    #pragma unroll
    for (int off = 1; off < 64; off <<= 1) {
      u64 o = shflx_u64(k, off);
      if (o > k) k = o;
    }
    if (lane == 0) partial[t & 1][w] = k;
    __syncthreads();
    u64 pk = partial[t & 1][lane & 7];
    #pragma unroll
    for (int off = 1; off < 8; off <<= 1) {
      u64 o = shflx_u64(pk, off);
      if (o > pk) pk = o;
    }
    const int idx = 2047 - (int)(pk & 0x7ff);
    if ((idx >> 2) == tid) mybits |= 1u << (idx & 3);
    if (tid == 0) selb[idx] = t;
  };

  float4 r0 = *(const float4*)(Sb + (size_t)0 * NN);
  float4 r1 = *(const float4*)(Sb + (size_t)1 * NN);
  float4 r2 = *(const float4*)(Sb + (size_t)2 * NN);
  float4 r3 = *(const float4*)(Sb + (size_t)3 * NN);
  for (int t = 0; t < NN; t += 4) {
    const size_t p4 = (size_t)((t + 4 < NN) ? t + 4 : NN - 1) * NN;
    const size_t p5 = (size_t)((t + 5 < NN) ? t + 5 : NN - 1) * NN;
    const size_t p6 = (size_t)((t + 6 < NN) ? t + 6 : NN - 1) * NN;
    const size_t p7 = (size_t)((t + 7 < NN) ? t + 7 : NN - 1) * NN;
    stepf(r0, t);     r0 = *(const float4*)(Sb + p4);
    stepf(r1, t + 1); r1 = *(const float4*)(Sb + p5);
    stepf(r2, t + 2); r2 = *(const float4*)(Sb + p6);
    stepf(r3, t + 3); r3 = *(const float4*)(Sb + p7);
  }
}

// ---------------------------------------------------------------------------
// Phase E: in-place masked softmax per row. Row t masks n iff sel[n] < t.
// ---------------------------------------------------------------------------
__global__ __launch_bounds__(256) void softmax_kernel(
    float* __restrict__ out, const int* __restrict__ sel)
{
  const int t = blockIdx.x;
  const int b = blockIdx.y;
  const int tid = threadIdx.x;
  float* row = out + ((size_t)b * NN + t) * NN;
  const int* selb = sel + b * NN;
  __shared__ float red[8];

  float v[8];
  int sl[8];
  #pragma unroll
  for (int u = 0; u < 2; ++u) {
    float4 f = *(const float4*)(row + u * 1024 + tid * 4);
    int4 s4 = *(const int4*)(selb + u * 1024 + tid * 4);
    v[u * 4 + 0] = f.x; v[u * 4 + 1] = f.y; v[u * 4 + 2] = f.z; v[u * 4 + 3] = f.w;
    sl[u * 4 + 0] = s4.x; sl[u * 4 + 1] = s4.y; sl[u * 4 + 2] = s4.z; sl[u * 4 + 3] = s4.w;
  }

  float mx = -3.0e38f;
  #pragma unroll
  for (int e = 0; e < 8; ++e)
    if (sl[e] >= t) mx = fmaxf(mx, v[e]);
  #pragma unroll
  for (int off = 1; off < 64; off <<= 1) mx = fmaxf(mx, __shfl_xor(mx, off));
  if ((tid & 63) == 0) red[tid >> 6] = mx;
  __syncthreads();
  mx = fmaxf(fmaxf(red[0], red[1]), fmaxf(red[2], red[3]));

  float e8[8];
  float sum = 0.f;
  #pragma unroll
  for (int e = 0; e < 8; ++e) {
    float ex = (sl[e] >= t) ? __expf(v[e] - mx) : 0.f;
    e8[e] = ex;
    sum += ex;
  }
  #pragma unroll
  for (int off = 1; off < 64; off <<= 1) sum += __shfl_xor(sum, off);
  if ((tid & 63) == 0) red[4 + (tid >> 6)] = sum;
  __syncthreads();
  sum = red[4] + red[5] + red[6] + red[7];
  const float inv = 1.f / sum;

  #pragma unroll
  for (int u = 0; u < 2; ++u) {
    float4 o;
    o.x = e8[u * 4 + 0] * inv; o.y = e8[u * 4 + 1] * inv;
    o.z = e8[u * 4 + 2] * inv; o.w = e8[u * 4 + 3] * inv;
    *(float4*)(row + u * 1024 + tid * 4) = o;
  }
}

// ---------------------------------------------------------------------------
// ws layout (floats): keys[4194304] | Q[4194304] | Pbuf(u64 4096 = 32KB,
//                     PACKED) | sel[16384]   ~ 33.7 MB
// Hall (h trajectory, [B][NN][256] f32 = 16.8MB) borrows d_out (134MB),
// consumed by the Q gemm before gemm2 overwrites it.
// ---------------------------------------------------------------------------
extern "C" void kernel_launch(void* const* d_in, const int* in_sizes, int n_in,
                              void* d_out, int out_size, void* d_ws, size_t ws_size,
                              hipStream_t stream)
{
  (void)in_sizes; (void)n_in; (void)out_size; (void)ws_size;
  const float* emb  = (const float*)d_in[0];
  const float* z_g  = (const float*)d_in[1];
  const float* dec  = (const float*)d_in[2];
  const float* h0   = (const float*)d_in[3];
  const float* w_ih = (const float*)d_in[4];
  const float* w_hh = (const float*)d_in[5];
  const float* b_ih = (const float*)d_in[6];
  const float* b_hh = (const float*)d_in[7];
  const float* Wq   = (const float*)d_in[8];
  const float* bq   = (const float*)d_in[9];
  const float* Wk   = (const float*)d_in[10];
  const float* bk   = (const float*)d_in[11];
  float* out = (float*)d_out;
  float* ws  = (float*)d_ws;

  float* keys  = ws;
  float* Q     = ws + 4194304;
  u64*   Pbuf  = (u64*)(ws + 8388608);    // 4096 u64 = 32 KB (packed)
  int*   sel   = (int*)(ws + 8396800);
  float* Hall  = out;                     // borrowed until the Q gemm

  // zero exchange tags (tag 0 never awaited; awaited tags >= 1)
  hipMemsetAsync(Pbuf, 0, 4096 * sizeof(u64), stream);

  lstm_kernel<<<dim3(NB, 8), 1024, 0, stream>>>(
      z_g, dec, h0, w_ih, w_hh, b_ih, b_hh, Hall, Pbuf);

  // Q = Hall @ Wq.T + bq  ([16384,256] x [256,256]^T)
  gemm128<<<dim3(MM / 128, (NB * NN) / 128, 1), 256, 0, stream>>>(
      Hall, Wq, Q, bq, MM, MM, 0, 0, 0);

  // keys = emb @ Wk.T + bk
  gemm128<<<dim3(MM / 128, (NB * NN) / 128, 1), 256, 0, stream>>>(
      emb, Wk, keys, bk, MM, MM, 0, 0, 0);

  // S[b] = Q[b] @ keys[b].T -> d_out (overwrites Hall, already consumed)
  gemm128<<<dim3(NN / 128, NN / 128, NB), 256, 0, stream>>>(
      Q, keys, out, nullptr, MM, NN,
      (long)NN * MM, (long)NN * MM, (long)NN * NN);

  select_block<<<NB, 512, 0, stream>>>(out, sel);

  softmax_kernel<<<dim3(NN, NB), 256, 0, stream>>>(out, sel);
}